// Round 1
// baseline (139.118 us; speedup 1.0000x reference)
//
#include <hip/hip_runtime.h>

#define BATCH 4096
#define IN_F 128
#define OUT_F 128
#define NW (IN_F * OUT_F)
#define BT 16          // b-rows per block
#define NBP 4          // b-rows per thread
// block = 512 threads = 128 o-columns x 4 b-groups; grid = BATCH/BT = 256

__global__ __launch_bounds__(512) void hypernet_fused(
    const float* __restrict__ x,        // (B,128)
    const float* __restrict__ feat,     // (B,10)
    const float* __restrict__ fc0W,     // (16,10)
    const float* __restrict__ fc0b,     // (16)
    const float* __restrict__ a0p,      // scalar
    const float* __restrict__ fc1W,     // (8,16)
    const float* __restrict__ fc1b,     // (8)
    const float* __restrict__ a1p,      // scalar
    const float* __restrict__ genW,     // (16512,8)
    const float* __restrict__ genb,     // (16512)
    float* __restrict__ out)            // (B,128)
{
    __shared__ float sX[BT][IN_F];      // 8 KB
    __shared__ float sH0[BT][16];       // layer-0 activations
    __shared__ float sH[BT][8];         // h1

    const int tid = threadIdx.x;
    const int b0 = blockIdx.x * BT;

    // ---- Phase A: tiny MLP, parallel over (b, unit) ----
    if (tid < BT * 16) {                // 256 threads: b = tid>>4, j = tid&15
        const int b = tid >> 4, j = tid & 15;
        const float a0 = a0p[0];
        float t = fc0b[j];
        const float* fr = feat + (size_t)(b0 + b) * 10;
        const float* wr = fc0W + j * 10;
#pragma unroll
        for (int m = 0; m < 10; m++) t += wr[m] * fr[m];
        sH0[b][j] = (t >= 0.f) ? t : a0 * t;
    }
    // ---- x tile: 16*128 floats = 512 float4, one per thread ----
    {
        const float4* xs = (const float4*)(x + (size_t)b0 * IN_F);
        ((float4*)&sX[0][0])[tid] = xs[tid];
    }
    __syncthreads();
    if (tid < BT * 8) {                 // 128 threads: b = tid>>3, n = tid&7
        const int b = tid >> 3, n = tid & 7;
        const float a1 = a1p[0];
        float t = fc1b[n];
        const float* wr = fc1W + n * 16;
#pragma unroll
        for (int j = 0; j < 16; j++) t += wr[j] * sH0[b][j];
        sH[b][n] = (t >= 0.f) ? t : a1 * t;
    }
    __syncthreads();

    // ---- Phase B: out[b,o] = sum_i (h1[b].gW[o,i,:] + gb[o,i]) * x[b,i] ----
    const int to = tid & 127;           // o column
    const int tg = tid >> 7;            // b-group 0..3

    float h[NBP][8];
#pragma unroll
    for (int t = 0; t < NBP; t++)
#pragma unroll
        for (int k = 0; k < 8; k++) h[t][k] = sH[tg * NBP + t][k];

    const float4* gW4 = (const float4*)(genW + (size_t)to * (IN_F * 8)); // o-slice: 128 rows x 8 f
    const float4* gB4 = (const float4*)(genb + (size_t)to * IN_F);
    float acc[NBP] = {0.f, 0.f, 0.f, 0.f};

#pragma unroll 2
    for (int ic = 0; ic < 16; ic++) {   // 8 i-rows per chunk
        float4 G[16];
#pragma unroll
        for (int j = 0; j < 16; j++) G[j] = gW4[ic * 16 + j];
        const float4 gb0 = gB4[ic * 2], gb1 = gB4[ic * 2 + 1];
        const float Gb[8] = {gb0.x, gb0.y, gb0.z, gb0.w, gb1.x, gb1.y, gb1.z, gb1.w};

#pragma unroll
        for (int t = 0; t < NBP; t++) {
            const int bl = tg * NBP + t;
            const float4 xa = ((const float4*)&sX[bl][0])[ic * 2];
            const float4 xb = ((const float4*)&sX[bl][0])[ic * 2 + 1];
            const float xs8[8] = {xa.x, xa.y, xa.z, xa.w, xb.x, xb.y, xb.z, xb.w};
#pragma unroll
            for (int ii = 0; ii < 8; ii++) {
                const float4 ga = G[2 * ii], gc = G[2 * ii + 1];
                float w = Gb[ii];
                w += ga.x * h[t][0] + ga.y * h[t][1] + ga.z * h[t][2] + ga.w * h[t][3];
                w += gc.x * h[t][4] + gc.y * h[t][5] + gc.z * h[t][6] + gc.w * h[t][7];
                acc[t] += w * xs8[ii];
            }
        }
    }

    // ---- epilogue: generated bias row NW+o ----
    const float* gwT = genW + (size_t)(NW + to) * 8;
    const float gbT = genb[NW + to];
#pragma unroll
    for (int t = 0; t < NBP; t++) {
        float tail = gbT;
#pragma unroll
        for (int k = 0; k < 8; k++) tail += gwT[k] * h[t][k];
        out[(size_t)(b0 + tg * NBP + t) * OUT_F + to] = acc[t] + tail;
    }
}

extern "C" void kernel_launch(void* const* d_in, const int* in_sizes, int n_in,
                              void* d_out, int out_size, void* d_ws, size_t ws_size,
                              hipStream_t stream) {
    const float* x     = (const float*)d_in[0];
    const float* feat  = (const float*)d_in[1];
    const float* fc0W  = (const float*)d_in[2];
    const float* fc0b  = (const float*)d_in[3];
    const float* a0    = (const float*)d_in[4];
    const float* fc1W  = (const float*)d_in[5];
    const float* fc1b  = (const float*)d_in[6];
    const float* a1    = (const float*)d_in[7];
    const float* genW  = (const float*)d_in[8];
    const float* genb  = (const float*)d_in[9];
    float* out = (float*)d_out;

    hypernet_fused<<<BATCH / BT, 512, 0, stream>>>(
        x, feat, fc0W, fc0b, a0, fc1W, fc1b, a1, genW, genb, out);
}

// Round 2
// 81.435 us; speedup vs baseline: 1.7083x; 1.7083x over previous
//
#include <hip/hip_runtime.h>
#include <hip/hip_bf16.h>

typedef __attribute__((ext_vector_type(8))) short short8;
typedef __attribute__((ext_vector_type(4))) float f32x4;

#define BATCH 4096
#define IN_F 128
#define OUT_F 128
#define NW (IN_F * OUT_F)          // 16384

// workspace layout (bytes)
#define WS_H1_OFF 0                // 4096*8 fp32   = 131072 B
#define WS_B_OFF  131072           // 18432*16 B    = 294912 B (bf16 B-fragments)
#define WS_A_OFF  425984           // 65536*16 B    = 1048576 B (bf16 A-fragments)

static __device__ __forceinline__ unsigned short f2bf(float f) {
    __hip_bfloat16 h = __float2bfloat16(f);
    unsigned short u;
    __builtin_memcpy(&u, &h, 2);
    return u;
}

// ---------------- prep: h1 MLP + pack G2 into B-fragments + pack x into A-fragments ----------------
// grid: 344 blocks x 256 = 88064 threads
//   [0, 18432): B_packed   (ot in [0,8), k9 in [0,9), kc in [0,4), lane in [0,64))
//   [18432, 18432+65536): A_packed (bt in [0,256), kc in [0,4), lane)
//   [83968, 88064): h1 MLP, one thread per b
__global__ __launch_bounds__(256) void prep_kernel(
    const float* __restrict__ x,
    const float* __restrict__ feat,
    const float* __restrict__ fc0W, const float* __restrict__ fc0b, const float* __restrict__ a0p,
    const float* __restrict__ fc1W, const float* __restrict__ fc1b, const float* __restrict__ a1p,
    const float* __restrict__ genW, const float* __restrict__ genb,
    unsigned char* __restrict__ ws)
{
    const int gid = blockIdx.x * 256 + threadIdx.x;

    if (gid < 18432) {
        // ---- B_packed: value(j) = G2[i = kc*32 + quad*8 + j][col = k9*128 + o], o = ot*16 + (lane&15)
        // G2[i][k*128+o]: k<8 -> genW[(o*128+i)*8 + k]; k==8 -> genb[o*128+i]
        const int lane = gid & 63;
        const int kc   = (gid >> 6) & 3;
        const int t2   = gid >> 8;          // [0, 72)
        const int k9   = t2 % 9;
        const int ot   = t2 / 9;
        const int quad = lane >> 4;
        const int o    = ot * 16 + (lane & 15);
        unsigned short v[8];
#pragma unroll
        for (int j = 0; j < 8; j++) {
            const int i = kc * 32 + quad * 8 + j;
            const float f = (k9 < 8) ? genW[(size_t)(o * 128 + i) * 8 + k9]
                                     : genb[o * 128 + i];
            v[j] = f2bf(f);
        }
        int4 pk;
        pk.x = (int)v[0] | ((int)v[1] << 16);
        pk.y = (int)v[2] | ((int)v[3] << 16);
        pk.z = (int)v[4] | ((int)v[5] << 16);
        pk.w = (int)v[6] | ((int)v[7] << 16);
        ((int4*)(ws + WS_B_OFF))[gid] = pk;
    } else if (gid < 18432 + 65536) {
        // ---- A_packed: value(j) = x[row = bt*16 + (lane&15)][col = kc*32 + quad*8 + j]
        const int id = gid - 18432;
        const int lane = id & 63;
        const int kc   = (id >> 6) & 3;
        const int bt   = id >> 8;           // [0, 256)
        const int row  = bt * 16 + (lane & 15);
        const int col  = kc * 32 + (lane >> 4) * 8;
        const float4* xp = (const float4*)(x + (size_t)row * IN_F + col);
        const float4 xa = xp[0], xb = xp[1];
        const float xs[8] = {xa.x, xa.y, xa.z, xa.w, xb.x, xb.y, xb.z, xb.w};
        unsigned short v[8];
#pragma unroll
        for (int j = 0; j < 8; j++) v[j] = f2bf(xs[j]);
        int4 pk;
        pk.x = (int)v[0] | ((int)v[1] << 16);
        pk.y = (int)v[2] | ((int)v[3] << 16);
        pk.z = (int)v[4] | ((int)v[5] << 16);
        pk.w = (int)v[6] | ((int)v[7] << 16);
        ((int4*)(ws + WS_A_OFF))[id] = pk;
    } else {
        // ---- tiny MLP -> h1
        const int b = gid - 18432 - 65536;  // [0, 4096)
        const float a0 = a0p[0], a1 = a1p[0];
        float f[10];
#pragma unroll
        for (int m = 0; m < 10; m++) f[m] = feat[(size_t)b * 10 + m];
        float h0[16];
#pragma unroll
        for (int j = 0; j < 16; j++) {
            float t = fc0b[j];
#pragma unroll
            for (int m = 0; m < 10; m++) t += fc0W[j * 10 + m] * f[m];
            h0[j] = (t >= 0.f) ? t : a0 * t;
        }
        float hv[8];
#pragma unroll
        for (int n = 0; n < 8; n++) {
            float t = fc1b[n];
#pragma unroll
            for (int j = 0; j < 16; j++) t += fc1W[n * 16 + j] * h0[j];
            hv[n] = (t >= 0.f) ? t : a1 * t;
        }
        float* h1o = (float*)(ws + WS_H1_OFF) + (size_t)b * 8;
        float4 p0 = {hv[0], hv[1], hv[2], hv[3]};
        float4 p1 = {hv[4], hv[5], hv[6], hv[7]};
        ((float4*)h1o)[0] = p0;
        ((float4*)h1o)[1] = p1;
    }
}

// ---------------- main: per wave 16 b-rows x 16 o's x 9 k-slices, K=128 via 4 MFMAs each ----------------
// grid: 512 blocks x 256 threads (4 waves). ot = blockIdx&7 (aligns with XCD round-robin),
// bg = blockIdx>>3. Wave w handles b-subtile bt = bg*4 + w.
__global__ __launch_bounds__(256, 2) void hypernet_mfma(
    const unsigned char* __restrict__ ws,
    const float* __restrict__ genW,
    const float* __restrict__ genb,
    float* __restrict__ out)
{
    const int lane = threadIdx.x & 63;
    const int w    = threadIdx.x >> 6;
    const int ot   = blockIdx.x & 7;
    const int bg   = blockIdx.x >> 3;
    const int bt   = bg * 4 + w;            // 16-row subtile [0,256)
    const int quad = lane >> 4;
    const int o    = ot * 16 + (lane & 15);

    // A fragments for this wave's 16 rows, all K=128
    const short8* Apk = (const short8*)(ws + WS_A_OFF);
    short8 a[4];
#pragma unroll
    for (int kc = 0; kc < 4; kc++) a[kc] = Apk[(bt * 4 + kc) * 64 + lane];

    const short8* Bpk = (const short8*)(ws + WS_B_OFF);
    f32x4 acc[9];
#pragma unroll
    for (int k = 0; k < 9; k++) acc[k] = (f32x4){0.f, 0.f, 0.f, 0.f};

#pragma unroll
    for (int k = 0; k < 9; k++) {
        const short8* bp = Bpk + (size_t)((ot * 9 + k) * 4) * 64 + lane;
        const short8 b0 = bp[0];
        const short8 b1 = bp[64];
        const short8 b2 = bp[128];
        const short8 b3 = bp[192];
        acc[k] = __builtin_amdgcn_mfma_f32_16x16x32_bf16(a[0], b0, acc[k], 0, 0, 0);
        acc[k] = __builtin_amdgcn_mfma_f32_16x16x32_bf16(a[1], b1, acc[k], 0, 0, 0);
        acc[k] = __builtin_amdgcn_mfma_f32_16x16x32_bf16(a[2], b2, acc[k], 0, 0, 0);
        acc[k] = __builtin_amdgcn_mfma_f32_16x16x32_bf16(a[3], b3, acc[k], 0, 0, 0);
    }

    // ---- epilogue (all in registers):
    // out[b,o] = sum_{k<8} h1[b,k]*(Y_k + genW[NW+o,k]) + Y_8 + genb[NW+o]
    const float4* gt4 = (const float4*)(genW + (size_t)(NW + o) * 8);
    const float4 g0 = gt4[0], g1 = gt4[1];
    const float gtv[8] = {g0.x, g0.y, g0.z, g0.w, g1.x, g1.y, g1.z, g1.w};
    const float gbt = genb[NW + o];

    const float* h1base = (const float*)(ws + WS_H1_OFF);
    const int brow0 = bg * 64 + w * 16 + quad * 4;

#pragma unroll
    for (int r = 0; r < 4; r++) {
        const float4* hp = (const float4*)(h1base + (size_t)(brow0 + r) * 8);
        const float4 ha = hp[0], hb = hp[1];
        const float hv[8] = {ha.x, ha.y, ha.z, ha.w, hb.x, hb.y, hb.z, hb.w};
        float s = acc[8][r] + gbt;
#pragma unroll
        for (int k = 0; k < 8; k++) s += hv[k] * (acc[k][r] + gtv[k]);
        out[(size_t)(brow0 + r) * OUT_F + o] = s;
    }
}

extern "C" void kernel_launch(void* const* d_in, const int* in_sizes, int n_in,
                              void* d_out, int out_size, void* d_ws, size_t ws_size,
                              hipStream_t stream) {
    const float* x     = (const float*)d_in[0];
    const float* feat  = (const float*)d_in[1];
    const float* fc0W  = (const float*)d_in[2];
    const float* fc0b  = (const float*)d_in[3];
    const float* a0    = (const float*)d_in[4];
    const float* fc1W  = (const float*)d_in[5];
    const float* fc1b  = (const float*)d_in[6];
    const float* a1    = (const float*)d_in[7];
    const float* genW  = (const float*)d_in[8];
    const float* genb  = (const float*)d_in[9];
    float* out = (float*)d_out;
    unsigned char* ws = (unsigned char*)d_ws;

    prep_kernel<<<344, 256, 0, stream>>>(x, feat, fc0W, fc0b, a0, fc1W, fc1b, a1, genW, genb, ws);
    hypernet_mfma<<<512, 256, 0, stream>>>(ws, genW, genb, out);
}

// Round 3
// 80.050 us; speedup vs baseline: 1.7379x; 1.0173x over previous
//
#include <hip/hip_runtime.h>
#include <hip/hip_bf16.h>

typedef __attribute__((ext_vector_type(8))) short short8;
typedef __attribute__((ext_vector_type(4))) float f32x4;

#define NW 16384
#define SB_STRIDE 136   // 128 + 8 pad: keeps LDS writes 2-way (free) and b128 reads balanced

static __device__ __forceinline__ unsigned short f2bf(float f) {
    __hip_bfloat16 h = __float2bfloat16(f);
    unsigned short u;
    __builtin_memcpy(&u, &h, 2);
    return u;
}

// One fused kernel. grid = 512 blocks x 256 threads.
// ot = blockIdx&7 (matches XCD round-robin -> per-XCD genW slice stays in its L2),
// bg = blockIdx>>3 -> 64 b-rows per block, 16 per wave.
__global__ __launch_bounds__(256, 2) void hypernet_fused(
    const float* __restrict__ x,        // (4096,128)
    const float* __restrict__ feat,     // (4096,10)
    const float* __restrict__ fc0W, const float* __restrict__ fc0b,
    const float* __restrict__ a0p,
    const float* __restrict__ fc1W, const float* __restrict__ fc1b,
    const float* __restrict__ a1p,
    const float* __restrict__ genW,     // (16512,8)
    const float* __restrict__ genb,     // (16512)
    float* __restrict__ out)            // (4096,128)
{
    __shared__ __attribute__((aligned(16))) unsigned short sB[16 * 9 * SB_STRIDE]; // 38.25 KB
    __shared__ float sH[64][8];                                                    // 2 KB

    const int tid = threadIdx.x;
    const int ot  = blockIdx.x & 7;
    const int bg  = blockIdx.x >> 3;
    const int b0  = bg * 64;

    // ---- stage genW o-slice (2048 contiguous rows x 8 cols = 64 KB) -> sB[o][k][i] bf16
    const float4* gw4 = (const float4*)(genW + (size_t)ot * 2048 * 8);
    #pragma unroll
    for (int j = 0; j < 8; j++) {
        const int idx = j * 256 + tid;          // (o,i): o = idx>>7, i = idx&127
        const int o = idx >> 7, i = idx & 127;
        const float4 p0 = gw4[idx * 2], p1 = gw4[idx * 2 + 1];
        const float v[8] = {p0.x, p0.y, p0.z, p0.w, p1.x, p1.y, p1.z, p1.w};
        #pragma unroll
        for (int k = 0; k < 8; k++)
            sB[(o * 9 + k) * SB_STRIDE + i] = f2bf(v[k]);
    }
    // ---- stage genb o-slice (2048 floats) -> k=8 plane
    const float4* gb4 = (const float4*)(genb + (size_t)ot * 2048);
    #pragma unroll
    for (int j = 0; j < 2; j++) {
        const int f = j * 256 + tid;            // float4 index [0,512)
        const int o = f >> 5, i = (f & 31) * 4;
        const float4 p = gb4[f];
        const float v[4] = {p.x, p.y, p.z, p.w};
        #pragma unroll
        for (int c = 0; c < 4; c++)
            sB[(o * 9 + 8) * SB_STRIDE + i + c] = f2bf(v[c]);
    }
    // ---- tiny MLP -> sH for this block's 64 rows
    if (tid < 64) {
        const int b = b0 + tid;
        const float a0 = a0p[0], a1 = a1p[0];
        float fv[10];
        #pragma unroll
        for (int m = 0; m < 10; m++) fv[m] = feat[(size_t)b * 10 + m];
        float h0[16];
        #pragma unroll
        for (int jj = 0; jj < 16; jj++) {
            float t = fc0b[jj];
            #pragma unroll
            for (int m = 0; m < 10; m++) t += fc0W[jj * 10 + m] * fv[m];
            h0[jj] = (t >= 0.f) ? t : a0 * t;
        }
        #pragma unroll
        for (int n = 0; n < 8; n++) {
            float t = fc1b[n];
            #pragma unroll
            for (int jj = 0; jj < 16; jj++) t += fc1W[n * 16 + jj] * h0[jj];
            sH[tid][n] = (t >= 0.f) ? t : a1 * t;
        }
    }
    __syncthreads();

    // ---- main: per wave 16 b-rows x 16 o's x 9 k-planes, K=128 via 4 MFMAs each
    const int lane = tid & 63;
    const int w    = tid >> 6;
    const int quad = lane >> 4;
    const int o16  = lane & 15;
    const int o    = ot * 16 + o16;

    // A fragments straight from global x (bf16 in-register)
    short8 a[4];
    const int arow = b0 + w * 16 + o16;          // MFMA A: m = lane&15
    #pragma unroll
    for (int kc = 0; kc < 4; kc++) {
        const float4* xp = (const float4*)(x + (size_t)arow * 128 + kc * 32 + quad * 8);
        const float4 xa = xp[0], xb = xp[1];
        const float v[8] = {xa.x, xa.y, xa.z, xa.w, xb.x, xb.y, xb.z, xb.w};
        short8 t;
        #pragma unroll
        for (int jj = 0; jj < 8; jj++) t[jj] = (short)f2bf(v[jj]);
        a[kc] = t;
    }

    f32x4 acc[9];
    #pragma unroll
    for (int k = 0; k < 9; k++) acc[k] = (f32x4){0.f, 0.f, 0.f, 0.f};

    #pragma unroll
    for (int k = 0; k < 9; k++) {
        const unsigned short* bp = sB + (o16 * 9 + k) * SB_STRIDE + quad * 8;
        const short8 bv0 = *(const short8*)(bp);
        const short8 bv1 = *(const short8*)(bp + 32);
        const short8 bv2 = *(const short8*)(bp + 64);
        const short8 bv3 = *(const short8*)(bp + 96);
        acc[k] = __builtin_amdgcn_mfma_f32_16x16x32_bf16(a[0], bv0, acc[k], 0, 0, 0);
        acc[k] = __builtin_amdgcn_mfma_f32_16x16x32_bf16(a[1], bv1, acc[k], 0, 0, 0);
        acc[k] = __builtin_amdgcn_mfma_f32_16x16x32_bf16(a[2], bv2, acc[k], 0, 0, 0);
        acc[k] = __builtin_amdgcn_mfma_f32_16x16x32_bf16(a[3], bv3, acc[k], 0, 0, 0);
    }

    // ---- epilogue: out[b,o] = sum_{k<8} h1[b,k]*(Y_k + genW[NW+o,k]) + Y_8 + genb[NW+o]
    const float4* gt4 = (const float4*)(genW + (size_t)(NW + o) * 8);
    const float4 g0 = gt4[0], g1 = gt4[1];
    const float gtv[8] = {g0.x, g0.y, g0.z, g0.w, g1.x, g1.y, g1.z, g1.w};
    const float gbt = genb[NW + o];

    const int brow0 = w * 16 + quad * 4;         // local row of C rows (C/D: row = quad*4+reg)
    #pragma unroll
    for (int r = 0; r < 4; r++) {
        const float* hp = sH[brow0 + r];
        float s = acc[8][r] + gbt;
        #pragma unroll
        for (int k = 0; k < 8; k++) s += hp[k] * (acc[k][r] + gtv[k]);
        out[(size_t)(b0 + brow0 + r) * 128 + o] = s;
    }
}

extern "C" void kernel_launch(void* const* d_in, const int* in_sizes, int n_in,
                              void* d_out, int out_size, void* d_ws, size_t ws_size,
                              hipStream_t stream) {
    const float* x     = (const float*)d_in[0];
    const float* feat  = (const float*)d_in[1];
    const float* fc0W  = (const float*)d_in[2];
    const float* fc0b  = (const float*)d_in[3];
    const float* a0    = (const float*)d_in[4];
    const float* fc1W  = (const float*)d_in[5];
    const float* fc1b  = (const float*)d_in[6];
    const float* a1    = (const float*)d_in[7];
    const float* genW  = (const float*)d_in[8];
    const float* genb  = (const float*)d_in[9];
    float* out = (float*)d_out;

    hypernet_fused<<<512, 256, 0, stream>>>(
        x, feat, fc0W, fc0b, a0, fc1W, fc1b, a1, genW, genb, out);
}

// Round 4
// 79.309 us; speedup vs baseline: 1.7541x; 1.0093x over previous
//
#include <hip/hip_runtime.h>
#include <hip/hip_bf16.h>

typedef __attribute__((ext_vector_type(8))) short short8;
typedef __attribute__((ext_vector_type(4))) float f32x4;

#define NW 16384
#define SB_STRIDE_U 68   // uints per (o,k) row: 64 data (128 bf16) + 4 pad

union U8 { unsigned int u[4]; short8 s; };

static __device__ __forceinline__ unsigned int pkbf(float a, float b) {
    float2 t; t.x = a; t.y = b;
    __hip_bfloat162 h = __float22bfloat162_rn(t);   // v_cvt_pk_bf16_f32 on gfx950
    unsigned int r; __builtin_memcpy(&r, &h, 4);
    return r;
}

// One fused kernel. grid = 512 blocks x 256 threads.
// ot = blockIdx&7 (XCD round-robin -> per-XCD genW slice L2-resident),
// bg = blockIdx>>3 -> 64 b-rows per block, 16 per wave.
__global__ __launch_bounds__(256, 2) void hypernet_fused(
    const float* __restrict__ x,        // (4096,128)
    const float* __restrict__ feat,     // (4096,10)
    const float* __restrict__ fc0W, const float* __restrict__ fc0b,
    const float* __restrict__ a0p,
    const float* __restrict__ fc1W, const float* __restrict__ fc1b,
    const float* __restrict__ a1p,
    const float* __restrict__ genW,     // (16512,8)
    const float* __restrict__ genb,     // (16512)
    float* __restrict__ out)            // (4096,128)
{
    __shared__ __attribute__((aligned(16))) unsigned int sB32[16 * 9 * SB_STRIDE_U]; // 39168 B
    __shared__ float sH[64][8];                                                      // 2 KB

    const int tid  = threadIdx.x;
    const int ot   = blockIdx.x & 7;
    const int bg   = blockIdx.x >> 3;
    const int b0   = bg * 64;
    const int lane = tid & 63;
    const int w    = tid >> 6;
    const int quad = lane >> 4;
    const int o16  = lane & 15;
    const int o    = ot * 16 + o16;

    // ---- issue latency-critical independent loads EARLY ----
    // A-fragment raw x rows (consumed after staging)
    float4 araw[8];
    const int arow = b0 + w * 16 + o16;
    #pragma unroll
    for (int kc = 0; kc < 4; kc++) {
        const float4* xp = (const float4*)(x + (size_t)arow * 128 + kc * 32 + quad * 8);
        araw[2 * kc]     = xp[0];
        araw[2 * kc + 1] = xp[1];
    }
    // epilogue tail (genW/genb rows NW..NW+127)
    const float4* gt4 = (const float4*)(genW + (size_t)(NW + o) * 8);
    const float4 g0 = gt4[0], g1 = gt4[1];
    const float gbt = genb[NW + o];

    // ---- stage genW o-slice -> sB[o][k][i] bf16, paired-i b32 writes ----
    const float4* gw4 = (const float4*)(genW + (size_t)ot * 2048 * 8);
    #pragma unroll
    for (int j = 0; j < 4; j++) {
        const int idx = j * 256 + tid;              // (o, ip): o = idx>>6, i = 2*ip
        const int oo = idx >> 6, ip = idx & 63;
        const int f4 = (oo * 128 + 2 * ip) * 2;     // float4 index of row i
        const float4 p0 = gw4[f4], p1 = gw4[f4 + 1];    // i:   k0..3, k4..7
        const float4 q0 = gw4[f4 + 2], q1 = gw4[f4 + 3];// i+1: k0..3, k4..7
        unsigned int* dst = sB32 + oo * 9 * SB_STRIDE_U + ip;
        dst[0 * SB_STRIDE_U] = pkbf(p0.x, q0.x);
        dst[1 * SB_STRIDE_U] = pkbf(p0.y, q0.y);
        dst[2 * SB_STRIDE_U] = pkbf(p0.z, q0.z);
        dst[3 * SB_STRIDE_U] = pkbf(p0.w, q0.w);
        dst[4 * SB_STRIDE_U] = pkbf(p1.x, q1.x);
        dst[5 * SB_STRIDE_U] = pkbf(p1.y, q1.y);
        dst[6 * SB_STRIDE_U] = pkbf(p1.z, q1.z);
        dst[7 * SB_STRIDE_U] = pkbf(p1.w, q1.w);
    }
    // ---- genb o-slice -> k=8 plane ----
    const float2* gb2 = (const float2*)(genb + (size_t)ot * 2048);
    #pragma unroll
    for (int j = 0; j < 4; j++) {
        const int idx = j * 256 + tid;
        const int oo = idx >> 6, ip = idx & 63;
        const float2 p = gb2[oo * 64 + ip];
        sB32[(oo * 9 + 8) * SB_STRIDE_U + ip] = pkbf(p.x, p.y);
    }
    // ---- tiny MLP -> sH (64 rows, one thread each) ----
    if (tid < 64) {
        const int b = b0 + tid;
        const float a0 = a0p[0], a1 = a1p[0];
        float fv[10];
        #pragma unroll
        for (int m = 0; m < 10; m++) fv[m] = feat[(size_t)b * 10 + m];
        float h0[16];
        #pragma unroll
        for (int jj = 0; jj < 16; jj++) {
            float t = fc0b[jj];
            #pragma unroll
            for (int m = 0; m < 10; m++) t += fc0W[jj * 10 + m] * fv[m];
            h0[jj] = (t >= 0.f) ? t : a0 * t;
        }
        #pragma unroll
        for (int n = 0; n < 8; n++) {
            float t = fc1b[n];
            #pragma unroll
            for (int jj = 0; jj < 16; jj++) t += fc1W[n * 16 + jj] * h0[jj];
            sH[tid][n] = (t >= 0.f) ? t : a1 * t;
        }
    }
    // ---- convert A-fragments (loads already landed) ----
    short8 a[4];
    #pragma unroll
    for (int kc = 0; kc < 4; kc++) {
        U8 t;
        const float4 va = araw[2 * kc], vb = araw[2 * kc + 1];
        t.u[0] = pkbf(va.x, va.y);
        t.u[1] = pkbf(va.z, va.w);
        t.u[2] = pkbf(vb.x, vb.y);
        t.u[3] = pkbf(vb.z, vb.w);
        a[kc] = t.s;
    }
    __syncthreads();

    // ---- main: 36 MFMAs (16b x 16o x 9 k-planes, K=128) ----
    const unsigned short* sBs = (const unsigned short*)sB32;
    f32x4 acc[9];
    #pragma unroll
    for (int k = 0; k < 9; k++) acc[k] = (f32x4){0.f, 0.f, 0.f, 0.f};

    #pragma unroll
    for (int k = 0; k < 9; k++) {
        const unsigned short* bp = sBs + (o16 * 9 + k) * (SB_STRIDE_U * 2) + quad * 8;
        const short8 bv0 = *(const short8*)(bp);
        const short8 bv1 = *(const short8*)(bp + 32);
        const short8 bv2 = *(const short8*)(bp + 64);
        const short8 bv3 = *(const short8*)(bp + 96);
        acc[k] = __builtin_amdgcn_mfma_f32_16x16x32_bf16(a[0], bv0, acc[k], 0, 0, 0);
        acc[k] = __builtin_amdgcn_mfma_f32_16x16x32_bf16(a[1], bv1, acc[k], 0, 0, 0);
        acc[k] = __builtin_amdgcn_mfma_f32_16x16x32_bf16(a[2], bv2, acc[k], 0, 0, 0);
        acc[k] = __builtin_amdgcn_mfma_f32_16x16x32_bf16(a[3], bv3, acc[k], 0, 0, 0);
    }

    // ---- epilogue: out[b,o] = sum_{k<8} h1[b,k]*(Y_k + gW_tail[k]) + Y_8 + gb_tail ----
    const float gtv[8] = {g0.x, g0.y, g0.z, g0.w, g1.x, g1.y, g1.z, g1.w};
    const int brow0 = w * 16 + quad * 4;    // C/D: row = quad*4 + reg
    #pragma unroll
    for (int r = 0; r < 4; r++) {
        const float4* hp4 = (const float4*)sH[brow0 + r];
        const float4 ha = hp4[0], hb = hp4[1];
        const float hv[8] = {ha.x, ha.y, ha.z, ha.w, hb.x, hb.y, hb.z, hb.w};
        float s = acc[8][r] + gbt;
        #pragma unroll
        for (int k = 0; k < 8; k++) s += hv[k] * (acc[k][r] + gtv[k]);
        out[(size_t)(b0 + brow0 + r) * 128 + o] = s;
    }
}

extern "C" void kernel_launch(void* const* d_in, const int* in_sizes, int n_in,
                              void* d_out, int out_size, void* d_ws, size_t ws_size,
                              hipStream_t stream) {
    const float* x     = (const float*)d_in[0];
    const float* feat  = (const float*)d_in[1];
    const float* fc0W  = (const float*)d_in[2];
    const float* fc0b  = (const float*)d_in[3];
    const float* a0    = (const float*)d_in[4];
    const float* fc1W  = (const float*)d_in[5];
    const float* fc1b  = (const float*)d_in[6];
    const float* a1    = (const float*)d_in[7];
    const float* genW  = (const float*)d_in[8];
    const float* genb  = (const float*)d_in[9];
    float* out = (float*)d_out;

    hypernet_fused<<<512, 256, 0, stream>>>(
        x, feat, fc0W, fc0b, a0, fc1W, fc1b, a1, genW, genb, out);
}